// Round 7
// baseline (531.405 us; speedup 1.0000x reference)
//
#include <hip/hip_runtime.h>
#include <cstddef>

// Problem constants
#define B_   4
#define NS_  96
#define T_   8
#define H_   256
#define N_   97      // NS + 1
#define NL_  6       // NUM_LAYERS
#define R_   388     // B_ * N_

// fast gates: v_exp_f32 (2^x) + v_rcp_f32
__device__ __forceinline__ float sigm(float x) {
    return __builtin_amdgcn_rcpf(1.0f + __builtin_amdgcn_exp2f(-1.44269504f * x));
}
__device__ __forceinline__ float tanh_f(float x) {
    return 1.0f - 2.0f * __builtin_amdgcn_rcpf(1.0f + __builtin_amdgcn_exp2f(2.88539008f * x));
}

// ---------------- gemm_v7: C[R,NC] = A[R,256] @ W[256,NC] (+bias) ----------------
// Tile 64(M) x 128(N), 256 thr, micro 8x4. A staged in LDS (r-major, conflict-free);
// W streamed from global as 4 independent b128 per 4k-block (L2-resident, prefetchable).
__global__ __launch_bounds__(256) void gemm_v7(const float* __restrict__ A,
        const int* __restrict__ ids, const float* __restrict__ embed,
        const float* __restrict__ W, const float* __restrict__ bias,
        float* __restrict__ C, int R, int NC) {
    __shared__ float As[64][260];    // 66.6 KB; pad 260 (16B-aligned rows)
    __shared__ int ridx[64];
    int t = threadIdx.x;
    int n0 = blockIdx.x * 128;
    int r0 = blockIdx.y * 64;
    if (ids) {
        if (t < 64) ridx[t] = (r0 + t < R) ? ids[r0 + t] : 0;
        __syncthreads();
    }
    // stage A tile 64x256 (16 float4 / thread, coalesced)
#pragma unroll
    for (int m = 0; m < 16; m++) {
        int L = m * 256 + t;
        int r = L >> 6, q4 = (L & 63) * 4;
        int rr = r0 + r;
        float4 v = make_float4(0.f, 0.f, 0.f, 0.f);
        if (rr < R) {
            const float* ap = ids ? (embed + (size_t)ridx[r] * 256)
                                  : (A + (size_t)rr * 256);
            v = *(const float4*)(ap + q4);
        }
        *(float4*)&As[r][q4] = v;
    }
    __syncthreads();
    int cg = t & 31;                 // 32 col-quads: cols n0 + 4cg..+3
    int rg = t >> 5;                 // 8 row-groups: rows r0 + 8rg..+7
    float acc[8][4] = {};
    const float* wp = W + n0 + 4 * cg;
#pragma unroll 2
    for (int kb = 0; kb < 64; kb++) {
        float4 w0 = *(const float4*)(wp + (size_t)(4 * kb + 0) * NC);
        float4 w1 = *(const float4*)(wp + (size_t)(4 * kb + 1) * NC);
        float4 w2 = *(const float4*)(wp + (size_t)(4 * kb + 2) * NC);
        float4 w3 = *(const float4*)(wp + (size_t)(4 * kb + 3) * NC);
#pragma unroll
        for (int i = 0; i < 8; i++) {
            float4 a = *(const float4*)&As[8 * rg + i][4 * kb];
            acc[i][0] = fmaf(a.x, w0.x, acc[i][0]);
            acc[i][1] = fmaf(a.x, w0.y, acc[i][1]);
            acc[i][2] = fmaf(a.x, w0.z, acc[i][2]);
            acc[i][3] = fmaf(a.x, w0.w, acc[i][3]);
            acc[i][0] = fmaf(a.y, w1.x, acc[i][0]);
            acc[i][1] = fmaf(a.y, w1.y, acc[i][1]);
            acc[i][2] = fmaf(a.y, w1.z, acc[i][2]);
            acc[i][3] = fmaf(a.y, w1.w, acc[i][3]);
            acc[i][0] = fmaf(a.z, w2.x, acc[i][0]);
            acc[i][1] = fmaf(a.z, w2.y, acc[i][1]);
            acc[i][2] = fmaf(a.z, w2.z, acc[i][2]);
            acc[i][3] = fmaf(a.z, w2.w, acc[i][3]);
            acc[i][0] = fmaf(a.w, w3.x, acc[i][0]);
            acc[i][1] = fmaf(a.w, w3.y, acc[i][1]);
            acc[i][2] = fmaf(a.w, w3.z, acc[i][2]);
            acc[i][3] = fmaf(a.w, w3.w, acc[i][3]);
        }
    }
    float4 bv = make_float4(0.f, 0.f, 0.f, 0.f);
    if (bias) bv = *(const float4*)&bias[n0 + 4 * cg];
#pragma unroll
    for (int i = 0; i < 8; i++) {
        int r = r0 + 8 * rg + i;
        if (r < R) {
            float4 o;
            o.x = acc[i][0] + bv.x;
            o.y = acc[i][1] + bv.y;
            o.z = acc[i][2] + bv.z;
            o.w = acc[i][3] + bv.w;
            *(float4*)&C[(size_t)r * NC + n0 + 4 * cg] = o;
        }
    }
}

// ---------------- tiny bias prep: cz[1024] = b_se@Wx_e + b_e ; ck[256] = b_se@W_sd + b_sd ----------------
__global__ void bias_prep(const float* __restrict__ b_se, const float* __restrict__ Wx_e,
                          const float* __restrict__ b_e, const float* __restrict__ W_sd,
                          const float* __restrict__ b_sd, float* __restrict__ cz,
                          float* __restrict__ ck) {
    __shared__ float a[256];
    int t = threadIdx.x;
    int n = blockIdx.x * 256 + t;    // 0..1279
    a[t] = b_se[t];
    __syncthreads();
    if (n < 1024) {
        float acc = b_e[n];
        for (int k = 0; k < 256; k++) acc = fmaf(a[k], Wx_e[k * 1024 + n], acc);
        cz[n] = acc;
    } else {
        int m = n - 1024;
        float acc = b_sd[m];
        for (int k = 0; k < 256; k++) acc = fmaf(a[k], W_sd[k * 256 + m], acc);
        ck[m] = acc;
    }
}

// ---------------- LSTM one step: distributed GEMM, 12 stripes x 16 col-tiles ----------------
__global__ void lstm_step(int step, const float* __restrict__ xz, const float* __restrict__ Wh,
                          float* __restrict__ hbuf, float* __restrict__ cbuf) {
    __shared__ float Wh_s[256][64];  // 64 KB
    __shared__ float h_s[32][260];
    __shared__ float zs[32][68];
    int t = threadIdx.x;             // 0..255
    int ct = blockIdx.x;             // col tile 0..15
    int st = blockIdx.y;             // stripe 0..11
    int et0 = ct * 16;
    int s0 = st * 32;
    int sp = t >> 4;
    int cq = t & 15;
    int g = cq >> 2, q4 = cq & 3;
    int gcol = g * 256 + et0 + q4 * 4;

    float4 a0, a1;
    {
        const float* x0 = xz + (((size_t)(s0 + sp)) * T_ + step) * 1024 + gcol;
        const float* x1 = xz + (((size_t)(s0 + sp + 16)) * T_ + step) * 1024 + gcol;
        a0 = *(const float4*)x0;
        a1 = *(const float4*)x1;
    }
    if (step > 0) {
#pragma unroll
        for (int m = 0; m < 16; m++) {
            int L = m * 256 + t;
            int k = L >> 4, f = L & 15;
            int gg = f >> 2, qq = f & 3;
            *(float4*)&Wh_s[k][f * 4] = *(const float4*)&Wh[(size_t)k * 1024 + gg * 256 + et0 + qq * 4];
        }
#pragma unroll
        for (int m = 0; m < 8; m++) {
            int L = m * 256 + t;
            int seq = L >> 6, c4 = (L & 63) * 4;
            *(float4*)&h_s[seq][c4] = *(const float4*)&hbuf[(size_t)(s0 + seq) * H_ + c4];
        }
        __syncthreads();
#pragma unroll 4
        for (int k = 0; k < 256; k++) {
            float4 w4 = *(const float4*)&Wh_s[k][cq * 4];
            float h0 = h_s[sp][k];
            float h1 = h_s[sp + 16][k];
            a0.x = fmaf(h0, w4.x, a0.x);
            a0.y = fmaf(h0, w4.y, a0.y);
            a0.z = fmaf(h0, w4.z, a0.z);
            a0.w = fmaf(h0, w4.w, a0.w);
            a1.x = fmaf(h1, w4.x, a1.x);
            a1.y = fmaf(h1, w4.y, a1.y);
            a1.z = fmaf(h1, w4.z, a1.z);
            a1.w = fmaf(h1, w4.w, a1.w);
        }
    }
    *(float4*)&zs[sp][cq * 4] = a0;
    *(float4*)&zs[sp + 16][cq * 4] = a1;
    __syncthreads();
    int seqA = t >> 4, e = t & 15;
#pragma unroll
    for (int u = 0; u < 2; u++) {
        int seq = seqA + u * 16;
        float gi = zs[seq][0 * 16 + e];
        float gf = zs[seq][1 * 16 + e];
        float gg = zs[seq][2 * 16 + e];
        float go = zs[seq][3 * 16 + e];
        size_t gidx = (size_t)(s0 + seq) * H_ + et0 + e;
        float cprev = (step > 0) ? cbuf[gidx] : 0.0f;
        float cnew = sigm(gf) * cprev + sigm(gi) * tanh_f(gg);
        cbuf[gidx] = cnew;
        hbuf[gidx] = sigm(go) * tanh_f(cnew);
    }
}

// ---------------- prefix sums over statements ----------------
__global__ void cumsum_k(const float* __restrict__ stmt, float* __restrict__ pref) {
    int b = blockIdx.x, t = threadIdx.x;
    float run = 0.0f;
    pref[((size_t)b * N_) * H_ + t] = 0.0f;
    for (int n = 1; n < N_; n++) {
        run += stmt[((size_t)b * NS_ + n - 1) * H_ + t];
        pref[((size_t)b * N_ + n) * H_ + t] = run;
    }
}

// ---------------- rT[b][h][n] = r[b][n][h] ----------------
__global__ void transpose_rT(const float* __restrict__ r, float* __restrict__ rT) {
    int row = blockIdx.x;            // 0..387
    int t = threadIdx.x;             // 0..255
    int b = row / N_, n = row % N_;
    rT[((size_t)b * H_ + t) * 128 + n] = r[(size_t)row * H_ + t];
}

// ---------------- init c/h/p ----------------
__global__ void init_state(const float* __restrict__ ia, const float* __restrict__ ib,
                           float* __restrict__ c0, float* __restrict__ h0,
                           float* __restrict__ p0) {
    int row = blockIdx.x, t = threadIdx.x;
    size_t idx = (size_t)row * H_ + t;
    c0[idx] = ia[t];
    h0[idx] = ib[t];
    if (t == 0) p0[row] = ((row % N_) == 0) ? 1.0f : 0.0f;
}

// ---------------- ONCE: logits + masked softmax, layer-invariant ----------------
// Writes spT_mid (middle-layer mask, transposed), spT0 (delta j=1), spT5 (delta j=len).
__global__ void softmax_once(const float* __restrict__ r, const float* __restrict__ rT,
                             const float* __restrict__ ck, const float* __restrict__ Wd1,
                             const int* __restrict__ code_length,
                             float* __restrict__ spT_mid, float* __restrict__ spT0,
                             float* __restrict__ spT5) {
    __shared__ float ri[H_], ckl[H_], wd[H_];
    __shared__ float part[8][128];
    __shared__ float red[128];
    int t = threadIdx.x;             // 0..1023
    int j = t & 127, half = t >> 7;  // 8 h-splits
    int bi = blockIdx.x;
    int b = bi / N_, i = bi % N_;
    if (t < H_) {
        ri[t] = r[(size_t)bi * H_ + t];
        ckl[t] = ck[t];
        wd[t] = Wd1[256 + t];
    }
    __syncthreads();
    int len = code_length[b] / T_;
    bool valid = (j < N_) && ((j > i && j <= len) || (j == len));  // middle-layer mask
    float acc = 0.0f;
    if (valid) {
        const float* rTb = rT + (size_t)b * H_ * 128 + j;
        int h0 = half * 32;
#pragma unroll 4
        for (int hh = 0; hh < 32; hh++) {
            int h = h0 + hh;
            float v = rTb[(size_t)h * 128] - ri[h] + ckl[h];
            acc = fmaf(fmaxf(v, 0.0f), wd[h], acc);
        }
    }
    part[half][j] = acc;
    __syncthreads();
    float logit = -3.0e38f;
    if (t < 128) {
        if (valid) {
            logit = part[0][j] + part[1][j] + part[2][j] + part[3][j]
                  + part[4][j] + part[5][j] + part[6][j] + part[7][j];
        }
        red[j] = logit;
    }
    __syncthreads();
    for (int off = 64; off > 0; off >>= 1) {
        if (t < off) red[t] = fmaxf(red[t], red[t + off]);
        __syncthreads();
    }
    float m = red[0];
    __syncthreads();
    float e = (t < 128 && valid) ? __builtin_amdgcn_exp2f(1.44269504f * (logit - m)) : 0.0f;
    if (t < 128) red[j] = e;
    __syncthreads();
    for (int off = 64; off > 0; off >>= 1) {
        if (t < off) red[t] += red[t + off];
        __syncthreads();
    }
    float s = red[0];
    if (t < 128 && j < N_) {
        size_t o = ((size_t)b * N_ + j) * 128 + i;   // transposed: [b][j][i]
        spT_mid[o] = e / s;
        spT0[o] = (j == 1) ? 1.0f : 0.0f;
        spT5[o] = (j == len) ? 1.0f : 0.0f;
    }
}

// ---------------- per-layer: gated propagation + weighted aggregation; 1024 thr ----------------
// w[i,j] = spT[b][j][i] * p[i] computed inline; early-exit when column has no mass.
__global__ void aggregate(const float* __restrict__ q, const float* __restrict__ he,
                          const float* __restrict__ spT, const float* __restrict__ p,
                          const float* __restrict__ ccur, const float* __restrict__ hcur,
                          float* __restrict__ cnxt, float* __restrict__ hnxt,
                          float* __restrict__ pnxt) {
    __shared__ float qj[1024];
    __shared__ float wcol[128];
    __shared__ float red[128];
    __shared__ int vlist[128];
    __shared__ int nv_s;
    __shared__ float wsum_s;
    __shared__ float parts[4][2][H_];
    int t = threadIdx.x;             // 0..1023
    int hh = t & 255, vs = t >> 8;   // 4 i-splits
    int bj = blockIdx.x;
    int b = bj / N_, j = bj % N_;
    if (t < 128) wcol[t] = (t < N_) ? spT[(size_t)bj * 128 + t] * p[(size_t)b * N_ + t] : 0.0f;
    __syncthreads();
    if (t < 128) red[t] = wcol[t];
    if (t == 0) {
        int nv = 0;
        for (int i = 0; i < N_; i++)
            if (wcol[i] != 0.0f) vlist[nv++] = i;
        nv_s = nv;
    }
    __syncthreads();
    for (int off = 64; off > 0; off >>= 1) {
        if (t < off) red[t] += red[t + off];
        __syncthreads();
    }
    if (t == 0) wsum_s = red[0];
    __syncthreads();
    float wsum = wsum_s;
    if (wsum == 0.0f) {              // no mass reaches j: outputs are exactly 0
        if (t < 256) {
            cnxt[(size_t)bj * H_ + t] = 0.0f;
            hnxt[(size_t)bj * H_ + t] = 0.0f;
            if (t == 0) pnxt[bj] = 0.0f;
        }
        return;
    }
    qj[t] = q[(size_t)bj * 1024 + t];
    __syncthreads();
    int nv = nv_s;
    float accc = 0.0f, acch = 0.0f;
    for (int v = vs; v < nv; v += 4) {
        int i = vlist[v];
        float wv = wcol[i];
        size_t rowi = (size_t)b * N_ + i;
        if (j > i) {
            const float* qi = q + rowi * 1024;
            const float* hei = he + rowi * 1024;
            float gi = qj[hh] - qi[hh] + hei[hh];
            float gf = qj[256 + hh] - qi[256 + hh] + hei[256 + hh];
            float gg = qj[512 + hh] - qi[512 + hh] + hei[512 + hh];
            float go = qj[768 + hh] - qi[768 + hh] + hei[768 + hh];
            float cc = ccur[rowi * H_ + hh];
            float cp = sigm(gf) * cc + sigm(gi) * tanh_f(gg);
            float hp = sigm(go) * tanh_f(cp);
            accc = fmaf(wv, cp, accc);
            acch = fmaf(wv, hp, acch);
        } else {
            accc = fmaf(wv, ccur[rowi * H_ + hh], accc);
            acch = fmaf(wv, hcur[rowi * H_ + hh], acch);
        }
    }
    parts[vs][0][hh] = accc;
    parts[vs][1][hh] = acch;
    __syncthreads();
    if (t < 256) {
        float inv = __builtin_amdgcn_rcpf(wsum + 1e-7f);
        float cs = parts[0][0][hh] + parts[1][0][hh] + parts[2][0][hh] + parts[3][0][hh];
        float hs = parts[0][1][hh] + parts[1][1][hh] + parts[2][1][hh] + parts[3][1][hh];
        cnxt[(size_t)bj * H_ + hh] = cs * inv;
        hnxt[(size_t)bj * H_ + hh] = hs * inv;
        if (t == 0) pnxt[bj] = wsum;
    }
}

// ---------------- host launcher ----------------

extern "C" void kernel_launch(void* const* d_in, const int* in_sizes, int n_in,
                              void* d_out, int out_size, void* d_ws, size_t ws_size,
                              hipStream_t stream) {
    const int*   code_statements = (const int*)d_in[0];
    const int*   code_length = (const int*)d_in[1];
    const float* embed = (const float*)d_in[2];
    const float* Wx_s = (const float*)d_in[3];
    const float* Wh_s = (const float*)d_in[4];
    const float* b_s  = (const float*)d_in[5];
    const float* W_se = (const float*)d_in[6];
    const float* b_se = (const float*)d_in[7];
    const float* Wx_e = (const float*)d_in[8];
    const float* Wh_e = (const float*)d_in[9];
    const float* b_e  = (const float*)d_in[10];
    const float* W_sd = (const float*)d_in[13];
    const float* b_sd = (const float*)d_in[14];
    const float* W_d1 = (const float*)d_in[15];
    // d_in[11] W_hk, d_in[12] b_hk, d_in[16] b_d1: softmax-invariant -> unused
    const float* init_a = (const float*)d_in[17];
    const float* init_b = (const float*)d_in[18];
    float* out = (float*)d_out;

    float* wsf = (float*)d_ws;
    size_t off = 0;
    auto alloc = [&](size_t n) { float* p = wsf + off; off += n; return p; };
    float* cz = alloc(1024);         // b_se @ Wx_e + b_e
    float* ck = alloc(256);          // b_se @ W_sd + b_sd
    float* xz = alloc((size_t)3072 * 1024);
    float* stmt = alloc(384 * 256);  // doubles as LSTM hbuf
    float* cls = alloc(384 * 256);   // LSTM cell state
    float* pref = alloc(R_ * 256);
    float* s_   = alloc(R_ * 256);   // pref @ W_se
    float* q  = alloc(R_ * 1024);
    float* r_ = alloc(R_ * 256);
    float* rT = alloc(4 * 256 * 128);
    float* he = alloc(R_ * 1024);
    float* spT_mid = alloc(R_ * 128);
    float* spT0    = alloc(R_ * 128);
    float* spT5    = alloc(R_ * 128);
    float* p0 = alloc(R_);
    float* p1 = alloc(R_);
    float* c0 = alloc(R_ * 256);
    float* c1 = alloc(R_ * 256);
    float* h0 = alloc(R_ * 256);
    float* h1 = alloc(R_ * 256);

    // statement encoder first (biggest grid); preps overlap-free but tiny
    gemm_v7<<<dim3(8, 48), 256, 0, stream>>>(nullptr, code_statements, embed, Wx_s, b_s,
                                             xz, 3072, 1024);
    bias_prep<<<dim3(5), 256, 0, stream>>>(b_se, Wx_e, b_e, W_sd, b_sd, cz, ck);
    init_state<<<dim3(R_), 256, 0, stream>>>(init_a, init_b, c0, h0, p0);
    for (int step = 0; step < T_; step++)
        lstm_step<<<dim3(16, 12), 256, 0, stream>>>(step, xz, Wh_s, stmt, cls);
    cumsum_k<<<dim3(4), 256, 0, stream>>>(stmt, pref);
    // s = pref @ W_se ; q = s @ Wx_e ; r = s @ W_sd   (M1/M2 prep eliminated)
    gemm_v7<<<dim3(2, 7), 256, 0, stream>>>(pref, nullptr, nullptr, W_se, nullptr,
                                            s_, R_, 256);
    gemm_v7<<<dim3(8, 7), 256, 0, stream>>>(s_, nullptr, nullptr, Wx_e, nullptr,
                                            q, R_, 1024);
    gemm_v7<<<dim3(2, 7), 256, 0, stream>>>(s_, nullptr, nullptr, W_sd, nullptr,
                                            r_, R_, 256);
    transpose_rT<<<dim3(R_), 256, 0, stream>>>(r_, rT);
    softmax_once<<<dim3(R_), 1024, 0, stream>>>(r_, rT, ck, W_d1, code_length,
                                                spT_mid, spT0, spT5);

    // execution layers
    for (int layer = 0; layer < NL_; layer++) {
        bool odd = (layer & 1);
        float* pc = odd ? p1 : p0;
        float* pn = odd ? p0 : p1;
        float* cc = odd ? c1 : c0;
        float* cn = odd ? c0 : c1;
        float* hc = odd ? h1 : h0;
        float* hn = odd ? h0 : h1;
        if (layer == NL_ - 1) hn = out;  // final h straight to d_out
        const float* spT = (layer == 0) ? spT0 : (layer == NL_ - 1) ? spT5 : spT_mid;
        gemm_v7<<<dim3(8, 7), 256, 0, stream>>>(hc, nullptr, nullptr, Wh_e, cz,
                                                he, R_, 1024);
        aggregate<<<dim3(R_), 1024, 0, stream>>>(q, he, spT, pc, cc, hc, cn, hn, pn);
    }
}